// Round 12
// baseline (26351.602 us; speedup 1.0000x reference)
//
#include <hip/hip_runtime.h>
#include <stdint.h>
#include <stddef.h>

#define T_STEPS 512
#define B_SZ    128
#define DIN     1024
#define H_SZ    2048
#define NG      8192            // 4*H
#define BH      (B_SZ * H_SZ)   // 262144

typedef __attribute__((ext_vector_type(8))) short bf16x8;
typedef __attribute__((ext_vector_type(16))) float f32x16;

static __device__ __forceinline__ unsigned short f2bf(float x) {
  unsigned int u = __float_as_uint(x);
  u += 0x7fffu + ((u >> 16) & 1u);   // RNE; inputs finite
  return (unsigned short)(u >> 16);
}

static __device__ __forceinline__ float sigm(float x) {
  return 1.0f / (1.0f + __expf(-x));
}
static __device__ __forceinline__ float tanh_(float x) {
  float e = __expf(-2.0f * fabsf(x));  // in (0,1], no overflow
  float t = (1.0f - e) / (1.0f + e);
  return x < 0.0f ? -t : t;
}

// global -> LDS async copy, 16B per lane. LDS dest is wave-uniform base;
// HW writes lane l at ldst + l*16. Global src IS per-lane (swizzle there).
static __device__ __forceinline__ void async_load16(const void* gsrc, void* ldst) {
  __builtin_amdgcn_global_load_lds(
      (__attribute__((address_space(1))) void*)(const_cast<void*>(gsrc)),
      (__attribute__((address_space(3))) void*)ldst,
      16, 0, 0);
}

// Barrier that memory ops cannot be compiler-moved across (rd4's NaN fix).
static __device__ __forceinline__ void wg_barrier_pinned() {
  __builtin_amdgcn_s_barrier();
  asm volatile("" ::: "memory");
  __builtin_amdgcn_sched_barrier(0);
}

__global__ void cvt_x_bf16(const float4* __restrict__ in, ushort4* __restrict__ out, int n4) {
  int i = blockIdx.x * blockDim.x + threadIdx.x;
  int st = gridDim.x * blockDim.x;
  for (; i < n4; i += st) {
    float4 v = in[i];
    ushort4 o;
    o.x = f2bf(v.x); o.y = f2bf(v.y); o.z = f2bf(v.z); o.w = f2bf(v.w);
    out[i] = o;
  }
}

__global__ void build_wcat(const float* __restrict__ wa, const float* __restrict__ wb,
                           unsigned short* __restrict__ outw, int ka, int K) {
  int k = blockIdx.x * blockDim.x + threadIdx.x;
  int n = blockIdx.y;
  if (k >= K) return;
  int kb = K - ka;
  float v = (k < ka) ? wa[(size_t)n * ka + k]
                     : wb[(size_t)n * kb + (k - ka)];
  outw[(size_t)n * K + k] = f2bf(v);
}

__global__ void init_state(const float* __restrict__ h0, const float* __restrict__ c0,
                           unsigned short* __restrict__ hb0, unsigned short* __restrict__ hb1,
                           float* __restrict__ cws) {
  int i = blockIdx.x * blockDim.x + threadIdx.x;
  if (i < BH) {
    hb0[i] = f2bf(h0[i]);
    hb1[i] = f2bf(h0[BH + i]);
    cws[i] = c0[i];
    cws[BH + i] = c0[BH + i];
  }
}

// One LSTM cell step, 32x32x16 MFMA. gates[128,8192] = A[128,K]@Wcat^T + b.
// WG tile = ALL 128 rows x 128 gate-cols (32 h-cols); traffic-minimal (mb=1).
// 256 threads = 4 waves; wave wv owns rows [wv*32, wv*32+32).
// acc[ct] (ct = gate) is f32x16; lane holds all 4 gates of 16 cells ->
// lane-local epilogue. A: direct global->register, 4 named sets, 4-ahead
// (4 x 16B frags per K-64 tile: k = c*16 + (lane>>5)*8, row = lane&31).
// B: LDS ring 4 x 16KB, staged 3 ahead via global_load_lds, XOR-swizzled.
// A/B share the same k-map so any k-permutation cancels in the dot product.
// Per-wave VMEM per iter: 4 stageB chunks + 4 loadA.
template<int K, int KSPLIT>
static __device__ __forceinline__ void lstm_step_body(
    unsigned short (*Bbuf)[128 * 64],
    const unsigned short* __restrict__ a0,   // [128][KSPLIT] row-major
    const unsigned short* __restrict__ a1,   // [128][H_SZ] row-major
    const unsigned short* __restrict__ w,    // [NG][K] bf16
    const float* __restrict__ bias,          // [NG] fp32
    float* __restrict__ c,                   // [B][H] fp32, in-place (tile-private)
    unsigned short* __restrict__ hout,       // [B][H] bf16
    float* __restrict__ fout,                // optional [B][H] fp32
    int tid, int lane, int wv, int n0h)      // n0h = cb*32 (h-col base)
{
  constexpr int KT = K >> 6;   // 48 or 64, divisible by 4
  f32x16 acc[4] = {};

  const int arow = wv * 32 + (lane & 31);
  const unsigned short* r0p = a0 + (size_t)arow * KSPLIT;
  const unsigned short* r1p = a1 + (size_t)arow * H_SZ;
  const int khi = (lane >> 5) << 3;   // k half-offset: 0 or 8 elems

  auto loadA = [&](int kt, bf16x8 (&A)[4]) {
    const int kb = kt << 6;
    const bool sA = kb < KSPLIT;     // tiles never straddle (KSPLIT % 64 == 0)
    const unsigned short* bp = (sA ? r0p : r1p) + (sA ? kb : kb - KSPLIT) + khi;
#pragma unroll
    for (int cc = 0; cc < 4; ++cc)
      A[cc] = *(const bf16x8*)(bp + cc * 16);
  };

  // B-tile 128 gate-rows x 64 k = 16KB = 1024 x 16B chunks; 4 per thread.
  // gate-row nl -> wcat row nn = (nl>>5)*2048 + n0h + (nl&31).
  auto stageB = [&](int kt) {
    const int kb = kt << 6;
#pragma unroll
    for (int it = 0; it < 4; ++it) {
      int cid = it * 256 + tid;
      int nl  = cid >> 3;                            // gate-row 0..127
      int chs = (cid & 7) ^ (nl & 7);                // pre-swizzled source chunk
      int nn  = ((nl >> 5) << 11) + n0h + (nl & 31);
      const unsigned short* src = w + (size_t)nn * K + kb + (chs << 3);
      async_load16(src, &Bbuf[kt & 3][(it * 256 + wv * 64) * 8]);
    }
  };

  auto iter = [&](int kt, bf16x8 (&A)[4]) {
    if (kt + 3 < KT) stageB(kt + 3);                 // issue stage early
    const int bq = kt & 3;
#pragma unroll
    for (int cc = 0; cc < 4; ++cc) {                 // K=16 chunks of the 64-tile
      const int chunk = (((cc << 1) + (lane >> 5)) ^ (lane & 7)) << 3;
      bf16x8 bfr[4];
#pragma unroll
      for (int ct = 0; ct < 4; ++ct)                 // ct = gate (32 cols each)
        bfr[ct] = *(const bf16x8*)&Bbuf[bq][(ct * 32 + (lane & 31)) * 64 + chunk];
#pragma unroll
      for (int ct = 0; ct < 4; ++ct)
        acc[ct] = __builtin_amdgcn_mfma_f32_32x32x16_bf16(A[cc], bfr[ct], acc[ct], 0, 0, 0);
    }
    if (kt + 4 < KT) loadA(kt + 4, A);               // refill own named set post-use
    // Ladder: retire own B(kt+1) (4 chunks, issued top of iter kt-2) before the
    // barrier. Ops after them: LA(kt+2)4 [rem>=2] + SB(kt+2)4 [rem>=2] +
    // LA(kt+3)4 [rem>=3] + SB(kt+3)4 [rem>=3] + LA(kt+4)4 [rem>=4].
    int rem = KT - 1 - kt;
    if (rem >= 4)      asm volatile("s_waitcnt vmcnt(20)" ::: "memory");
    else if (rem == 3) asm volatile("s_waitcnt vmcnt(16)" ::: "memory");
    else if (rem == 2) asm volatile("s_waitcnt vmcnt(8)"  ::: "memory");
    else if (rem == 1) asm volatile("s_waitcnt vmcnt(0)"  ::: "memory");
    if (rem > 0) wg_barrier_pinned();   // last iter: no reuse after -> no barrier
  };

  // Entry guard: prologue counts assume an empty vmcnt FIFO (prior epilogue
  // stores/loads share it).
  asm volatile("s_waitcnt vmcnt(0)" ::: "memory");

  bf16x8 A0[4], A1[4], A2[4], A3[4];
  // Prologue queue: B0x4,A0x4,B1x4,A1x4,B2x4,A2x4,A3x4 = 28 ops; retire B0 -> 24.
  stageB(0); loadA(0, A0);
  stageB(1); loadA(1, A1);
  stageB(2); loadA(2, A2);
  loadA(3, A3);
  asm volatile("s_waitcnt vmcnt(24)" ::: "memory");
  wg_barrier_pinned();

  for (int kt = 0; kt < KT; kt += 4) {
    iter(kt,     A0);
    iter(kt + 1, A1);
    iter(kt + 2, A2);
    iter(kt + 3, A3);
  }

  // Epilogue (lane-local). 32x32 C/D map [m74/m101]: col = lane&31,
  // row_local = (reg&3) + 8*(reg>>2) + 4*(lane>>5); acc[ct] -> gate ct.
  const int hc = n0h + (lane & 31);
  const float bi  = bias[hc];
  const float bff = bias[H_SZ + hc];
  const float bg  = bias[2 * H_SZ + hc];
  const float bo  = bias[3 * H_SZ + hc];
  const int rbase = wv * 32 + ((lane >> 5) << 2);

#pragma unroll
  for (int reg = 0; reg < 16; ++reg) {
    int row = rbase + (reg & 3) + ((reg >> 2) << 3);
    size_t idx = (size_t)row * H_SZ + hc;
    float iv = sigm(acc[0][reg] + bi);
    float fv = sigm(acc[1][reg] + bff);
    float gv = tanh_(acc[2][reg] + bg);
    float ov = sigm(acc[3][reg] + bo);
    float cn = fv * c[idx] + iv * gv;
    c[idx] = cn;
    float hn = ov * tanh_(cn);
    hout[idx] = f2bf(hn);
    if (fout) fout[idx] = hn;
  }
}

// Single step (edges of the schedule). Grid 64 (32 h-cols per WG).
template<int K, int KSPLIT>
__global__ __launch_bounds__(256) void lstm_one(
    const unsigned short* __restrict__ a0, const unsigned short* __restrict__ a1,
    const unsigned short* __restrict__ w,  const float* __restrict__ bias,
    float* __restrict__ c, unsigned short* __restrict__ hout, float* __restrict__ fout)
{
  __shared__ __align__(16) unsigned short Bbuf[4][128 * 64];   // 64 KB
  const int tid = threadIdx.x, lane = tid & 63, wv = tid >> 6;
  const int n0h = blockIdx.x << 5;
  lstm_step_body<K, KSPLIT>(Bbuf, a0, a1, w, bias, c, hout, fout, tid, lane, wv, n0h);
}

// Layer-split pair: grid 128. WGs 0..63 run L1(t), WGs 64..127 run L0(t+1)
// CONCURRENTLY (independent: both read only buffers published at the
// preceding dispatch boundary; writes are disjoint and read only after the
// next boundary). Wall per pair = max(L1, L0) instead of L1 + L0.
template<int K1, int KS1, int K2, int KS2>
__global__ __launch_bounds__(256) void lstm_pair(
    const unsigned short* __restrict__ a0_1, const unsigned short* __restrict__ a1_1,
    const unsigned short* __restrict__ w1,   const float* __restrict__ bias1,
    float* __restrict__ c1, unsigned short* __restrict__ h1out,
    const unsigned short* __restrict__ a0_2, const unsigned short* __restrict__ a1_2,
    const unsigned short* __restrict__ w2,   const float* __restrict__ bias2,
    float* __restrict__ c2, unsigned short* __restrict__ h2out)
{
  __shared__ __align__(16) unsigned short Bbuf[4][128 * 64];   // 64 KB
  const int tid = threadIdx.x, lane = tid & 63, wv = tid >> 6;
  if (blockIdx.x < 64) {
    const int n0h = blockIdx.x << 5;
    lstm_step_body<K1, KS1>(Bbuf, a0_1, a1_1, w1, bias1, c1, h1out, nullptr, tid, lane, wv, n0h);
  } else {
    const int n0h = (blockIdx.x - 64) << 5;
    lstm_step_body<K2, KS2>(Bbuf, a0_2, a1_2, w2, bias2, c2, h2out, nullptr, tid, lane, wv, n0h);
  }
}

extern "C" void kernel_launch(void* const* d_in, const int* in_sizes, int n_in,
                              void* d_out, int out_size, void* d_ws, size_t ws_size,
                              hipStream_t stream) {
  (void)in_sizes; (void)n_in; (void)out_size; (void)ws_size;
  const float* x    = (const float*)d_in[0];
  const float* h0   = (const float*)d_in[1];
  const float* c0   = (const float*)d_in[2];
  const float* Wih0 = (const float*)d_in[3];
  const float* Whh0 = (const float*)d_in[4];
  const float* b0   = (const float*)d_in[5];
  const float* Wih1 = (const float*)d_in[6];
  const float* Whh1 = (const float*)d_in[7];
  const float* b1   = (const float*)d_in[8];
  float* out = (float*)d_out;

  unsigned short* xbf = (unsigned short*)d_ws;                     // 512*128*1024 bf16
  unsigned short* Wc0 = xbf + (size_t)T_STEPS * B_SZ * DIN;        // 8192*3072
  unsigned short* Wc1 = Wc0 + (size_t)NG * 3072;                   // 8192*4096
  unsigned short* hb0 = Wc1 + (size_t)NG * 4096;                   // 2 * BH (ping-pong)
  unsigned short* hb1 = hb0 + 2 * (size_t)BH;                      // 2 * BH
  float*          cws = (float*)(hb1 + 2 * (size_t)BH);            // 2 * BH fp32

  cvt_x_bf16<<<dim3(4096), dim3(256), 0, stream>>>(
      (const float4*)x, (ushort4*)xbf, T_STEPS * B_SZ * DIN / 4);
  build_wcat<<<dim3(12, NG), dim3(256), 0, stream>>>(Wih0, Whh0, Wc0, DIN, 3072);
  build_wcat<<<dim3(16, NG), dim3(256), 0, stream>>>(Wih1, Whh1, Wc1, H_SZ, 4096);
  init_state<<<dim3(BH / 256), dim3(256), 0, stream>>>(h0, c0, hb0, hb1, cws);

  // Schedule: L0(0); { L1(t) || L0(t+1) } t=0..510; L1(511)->out.
  // h slots: L0(t) reads hb0 slot[t&1], writes slot[(t+1)&1];
  //          L1(t) reads hb0 slot[(t+1)&1] + hb1 slot[t&1], writes hb1 slot[(t+1)&1].
  lstm_one<3072, 1024><<<dim3(64), dim3(256), 0, stream>>>(
      xbf, hb0 + 0, Wc0, b0, cws, hb0 + BH, nullptr);

  for (int t = 0; t < T_STEPS - 1; ++t) {
    const unsigned short* h0cur = hb0 + (size_t)((t + 1) & 1) * BH;
    lstm_pair<4096, 2048, 3072, 1024><<<dim3(128), dim3(256), 0, stream>>>(
        /*L1(t)*/   h0cur, hb1 + (size_t)(t & 1) * BH, Wc1, b1,
                    cws + BH, hb1 + (size_t)((t + 1) & 1) * BH,
        /*L0(t+1)*/ xbf + (size_t)(t + 1) * B_SZ * DIN, h0cur, Wc0, b0,
                    cws, hb0 + (size_t)(t & 1) * BH);
  }
  // L1(511): reads hb0 slot0, hb1 slot1; writes hb1 slot0 + fp32 out.
  lstm_one<4096, 2048><<<dim3(64), dim3(256), 0, stream>>>(
      hb0 + 0, hb1 + BH, Wc1, b1, cws + BH, hb1 + 0, out);
}

// Round 13
// 21684.422 us; speedup vs baseline: 1.2152x; 1.2152x over previous
//
#include <hip/hip_runtime.h>
#include <stdint.h>
#include <stddef.h>

#define T_STEPS 512
#define B_SZ    128
#define DIN     1024
#define H_SZ    2048
#define NG      8192            // 4*H
#define BH      (B_SZ * H_SZ)   // 262144

typedef __attribute__((ext_vector_type(8))) short bf16x8;
typedef __attribute__((ext_vector_type(16))) float f32x16;

static __device__ __forceinline__ unsigned short f2bf(float x) {
  unsigned int u = __float_as_uint(x);
  u += 0x7fffu + ((u >> 16) & 1u);   // RNE; inputs finite
  return (unsigned short)(u >> 16);
}

static __device__ __forceinline__ float sigm(float x) {
  return 1.0f / (1.0f + __expf(-x));
}
static __device__ __forceinline__ float tanh_(float x) {
  float e = __expf(-2.0f * fabsf(x));  // in (0,1], no overflow
  float t = (1.0f - e) / (1.0f + e);
  return x < 0.0f ? -t : t;
}

// global -> LDS async copy, 16B per lane (wave-uniform LDS base).
static __device__ __forceinline__ void async_load16(const void* gsrc, void* ldst) {
  __builtin_amdgcn_global_load_lds(
      (__attribute__((address_space(1))) void*)(const_cast<void*>(gsrc)),
      (__attribute__((address_space(3))) void*)ldst,
      16, 0, 0);
}

// Barrier that memory ops cannot be compiler-moved across (rd4's NaN fix).
static __device__ __forceinline__ void wg_barrier_pinned() {
  __builtin_amdgcn_s_barrier();
  asm volatile("" ::: "memory");
  __builtin_amdgcn_sched_barrier(0);
}

// Producer/consumer handshake between k-half WGs (rd3-validated pattern).
static __device__ __forceinline__ void publish(unsigned* flag, unsigned epoch) {
  __syncthreads();                       // drains each thread's stores (vmcnt 0)
  if (threadIdx.x == 0) {
    __threadfence();                     // agent-scope release fence
    __hip_atomic_store(flag, epoch, __ATOMIC_RELEASE, __HIP_MEMORY_SCOPE_AGENT);
  }
}
static __device__ __forceinline__ void await(const unsigned* flag, unsigned epoch) {
  if (threadIdx.x == 0)
    while (__hip_atomic_load(flag, __ATOMIC_ACQUIRE, __HIP_MEMORY_SCOPE_AGENT) < epoch)
      __builtin_amdgcn_s_sleep(8);
  __syncthreads();
}

__global__ void cvt_x_bf16(const float4* __restrict__ in, ushort4* __restrict__ out, int n4) {
  int i = blockIdx.x * blockDim.x + threadIdx.x;
  int st = gridDim.x * blockDim.x;
  for (; i < n4; i += st) {
    float4 v = in[i];
    ushort4 o;
    o.x = f2bf(v.x); o.y = f2bf(v.y); o.z = f2bf(v.z); o.w = f2bf(v.w);
    out[i] = o;
  }
}

__global__ void build_wcat(const float* __restrict__ wa, const float* __restrict__ wb,
                           unsigned short* __restrict__ outw, int ka, int K) {
  int k = blockIdx.x * blockDim.x + threadIdx.x;
  int n = blockIdx.y;
  if (k >= K) return;
  int kb = K - ka;
  float v = (k < ka) ? wa[(size_t)n * ka + k]
                     : wb[(size_t)n * kb + (k - ka)];
  outw[(size_t)n * K + k] = f2bf(v);
}

__global__ void init_state(const float* __restrict__ h0, const float* __restrict__ c0,
                           unsigned short* __restrict__ hb0, unsigned short* __restrict__ hb1,
                           float* __restrict__ cws, unsigned* __restrict__ flags) {
  int i = blockIdx.x * blockDim.x + threadIdx.x;
  if (i < 256) flags[i] = 0u;            // re-zero ALL flag slots every launch
  if (i < BH) {
    hb0[i] = f2bf(h0[i]);
    hb1[i] = f2bf(h0[BH + i]);
    cws[i] = c0[i];
    cws[BH + i] = c0[BH + i];
  }
}

// K-half GEMM, 32x32x16 MFMA (rd12-verified layouts). Computes a 128x128
// gate-tile partial over k in [kofs, kofs + KT*64). A = concat(a0|a1) at
// ksplit (64-aligned). 256 thr = 4 waves; wave wv owns rows [wv*32, +32).
// A: direct global->reg, 4 named sets, 4-ahead. B: LDS ring 4x16KB, staged
// 3 ahead via global_load_lds, XOR-swizzled. Per-wave/iter: 4 SB + 4 LA.
template<int KT>
static __device__ __forceinline__ void gemm_ks(
    unsigned short (*Bbuf)[128 * 64],
    const unsigned short* __restrict__ a0, int s0, int ksplit,
    const unsigned short* __restrict__ a1,          // row stride H_SZ
    int kofs,
    const unsigned short* __restrict__ w, int wstr, // [NG][wstr] bf16
    int tid, int lane, int wv, int n0h,
    f32x16 (&acc)[4])
{
  const int arow = wv * 32 + (lane & 31);
  const unsigned short* r0p = a0 + (size_t)arow * s0;
  const unsigned short* r1p = a1 + (size_t)arow * H_SZ;
  const int khi = (lane >> 5) << 3;   // k half-offset: 0 or 8 elems

  auto loadA = [&](int kt, bf16x8 (&A)[4]) {
    const int kbg = kofs + (kt << 6);
    const bool sA = kbg < ksplit;     // 64-tiles never straddle
    const unsigned short* bp = (sA ? r0p + kbg : r1p + (kbg - ksplit)) + khi;
#pragma unroll
    for (int cc = 0; cc < 4; ++cc)
      A[cc] = *(const bf16x8*)(bp + cc * 16);
  };

  auto stageB = [&](int kt) {
    const int kbg = kofs + (kt << 6);
#pragma unroll
    for (int it = 0; it < 4; ++it) {
      int cid = it * 256 + tid;
      int nl  = cid >> 3;                            // gate-row 0..127
      int chs = (cid & 7) ^ (nl & 7);                // pre-swizzled source chunk
      int nn  = ((nl >> 5) << 11) + n0h + (nl & 31);
      const unsigned short* src = w + (size_t)nn * wstr + kbg + (chs << 3);
      async_load16(src, &Bbuf[kt & 3][(it * 256 + wv * 64) * 8]);
    }
  };

  auto iter = [&](int kt, bf16x8 (&A)[4]) {
    if (kt + 3 < KT) stageB(kt + 3);
    const int bq = kt & 3;
#pragma unroll
    for (int cc = 0; cc < 4; ++cc) {
      const int chunk = (((cc << 1) + (lane >> 5)) ^ (lane & 7)) << 3;
      bf16x8 bfr[4];
#pragma unroll
      for (int ct = 0; ct < 4; ++ct)
        bfr[ct] = *(const bf16x8*)&Bbuf[bq][(ct * 32 + (lane & 31)) * 64 + chunk];
#pragma unroll
      for (int ct = 0; ct < 4; ++ct)
        acc[ct] = __builtin_amdgcn_mfma_f32_32x32x16_bf16(A[cc], bfr[ct], acc[ct], 0, 0, 0);
    }
    if (kt + 4 < KT) loadA(kt + 4, A);
    // Retire own B(kt+1) before the barrier (in-order vmcnt FIFO count).
    int rem = KT - 1 - kt;
    if (rem >= 4)      asm volatile("s_waitcnt vmcnt(20)" ::: "memory");
    else if (rem == 3) asm volatile("s_waitcnt vmcnt(16)" ::: "memory");
    else if (rem == 2) asm volatile("s_waitcnt vmcnt(8)"  ::: "memory");
    else if (rem == 1) asm volatile("s_waitcnt vmcnt(0)"  ::: "memory");
    if (rem > 0) wg_barrier_pinned();
  };

  asm volatile("s_waitcnt vmcnt(0)" ::: "memory");   // entry guard

  bf16x8 A0[4], A1[4], A2[4], A3[4];
  stageB(0); loadA(0, A0);
  stageB(1); loadA(1, A1);
  stageB(2); loadA(2, A2);
  loadA(3, A3);
  asm volatile("s_waitcnt vmcnt(24)" ::: "memory");  // retire B0
  wg_barrier_pinned();

  for (int kt = 0; kt < KT; kt += 4) {
    iter(kt,     A0);
    iter(kt + 1, A1);
    iter(kt + 2, A2);
    iter(kt + 3, A3);
  }
}

// Partial exchange: layout p[ct][row][col] fp32 (coalesced: 32 lanes = 32
// consecutive cols). Writer and reader lanes hold identical (row,col,ct).
static __device__ __forceinline__ void store_partial(
    const f32x16 (&acc)[4], float* __restrict__ p, int lane, int wv) {
  const int col = lane & 31;
  const int rbase = wv * 32 + ((lane >> 5) << 2);
#pragma unroll
  for (int ct = 0; ct < 4; ++ct)
#pragma unroll
    for (int reg = 0; reg < 16; ++reg) {
      int row = rbase + (reg & 3) + ((reg >> 2) << 3);
      p[((ct << 7) + row) * 32 + col] = acc[ct][reg];
    }
}
static __device__ __forceinline__ void combine_add(
    f32x16 (&acc)[4], const float* __restrict__ p, int lane, int wv) {
  const int col = lane & 31;
  const int rbase = wv * 32 + ((lane >> 5) << 2);
#pragma unroll
  for (int ct = 0; ct < 4; ++ct)
#pragma unroll
    for (int reg = 0; reg < 16; ++reg) {
      int row = rbase + (reg & 3) + ((reg >> 2) << 3);
      acc[ct][reg] += p[((ct << 7) + row) * 32 + col];
    }
}

// Epilogue (lane-local; rd12-verified C/D map: col=lane&31,
// row_local=(reg&3)+8*(reg>>2)+4*(lane>>5); acc[ct] = gate ct).
static __device__ __forceinline__ void lstm_epilogue(
    const f32x16 (&acc)[4], const float* __restrict__ bias,
    float* __restrict__ c, unsigned short* __restrict__ hout,
    float* __restrict__ fout, int lane, int wv, int n0h) {
  const int hc = n0h + (lane & 31);
  const float bi  = bias[hc];
  const float bff = bias[H_SZ + hc];
  const float bg  = bias[2 * H_SZ + hc];
  const float bo  = bias[3 * H_SZ + hc];
  const int rbase = wv * 32 + ((lane >> 5) << 2);
#pragma unroll
  for (int reg = 0; reg < 16; ++reg) {
    int row = rbase + (reg & 3) + ((reg >> 2) << 3);
    size_t idx = (size_t)row * H_SZ + hc;
    float iv = sigm(acc[0][reg] + bi);
    float fv = sigm(acc[1][reg] + bff);
    float gv = tanh_(acc[2][reg] + bg);
    float ov = sigm(acc[3][reg] + bo);
    float cn = fv * c[idx] + iv * gv;
    c[idx] = cn;
    float hn = ov * tanh_(cn);
    hout[idx] = f2bf(hn);
    if (fout) fout[idx] = hn;
  }
}

// Pair dispatch, K-split: grid 256 = 4 roles x 64 col-blocks. All WGs
// co-resident (1/CU) -> intra-dispatch flag handshake is deadlock-free.
// roles: 0 = L1(t) k[0,2048) + combine/epilogue; 1 = L1(t) k[2048,4096) partial;
//        2 = L0(t+1) k[0,1536) + combine/epilogue; 3 = L0(t+1) k[1536,3072) partial.
template<int KT1, int KT0>
__global__ __launch_bounds__(256) void lstm_pair_ks(
    const unsigned short* __restrict__ h0cur,   // L1 a0 (stride H_SZ) & L0 a1
    const unsigned short* __restrict__ h1prev,  // L1 a1
    const unsigned short* __restrict__ Wc1, const float* __restrict__ b1,
    float* __restrict__ c1, unsigned short* __restrict__ h1out,
    const unsigned short* __restrict__ xsl,     // L0 a0 (stride DIN)
    const unsigned short* __restrict__ Wc0, const float* __restrict__ b0,
    float* __restrict__ c0, unsigned short* __restrict__ h0out,
    float* __restrict__ p1, float* __restrict__ p0,
    unsigned* __restrict__ f1, unsigned* __restrict__ f0, unsigned epoch)
{
  __shared__ __align__(16) unsigned short Bbuf[4][128 * 64];   // 64 KB
  const int tid = threadIdx.x, lane = tid & 63, wv = tid >> 6;
  const int role = blockIdx.x >> 6, cb = blockIdx.x & 63, n0h = cb << 5;
  f32x16 acc[4] = {};

  if (role == 0) {
    gemm_ks<KT1>(Bbuf, h0cur, H_SZ, 2048, h1prev, 0, Wc1, 4096, tid, lane, wv, n0h, acc);
    await(f1 + cb, epoch);
    combine_add(acc, p1 + (size_t)cb * 16384, lane, wv);
    lstm_epilogue(acc, b1, c1, h1out, nullptr, lane, wv, n0h);
  } else if (role == 1) {
    gemm_ks<KT1>(Bbuf, h0cur, H_SZ, 2048, h1prev, 2048, Wc1, 4096, tid, lane, wv, n0h, acc);
    store_partial(acc, p1 + (size_t)cb * 16384, lane, wv);
    publish(f1 + cb, epoch);
  } else if (role == 2) {
    gemm_ks<KT0>(Bbuf, xsl, DIN, 1024, h0cur, 0, Wc0, 3072, tid, lane, wv, n0h, acc);
    await(f0 + cb, epoch);
    combine_add(acc, p0 + (size_t)cb * 16384, lane, wv);
    lstm_epilogue(acc, b0, c0, h0out, nullptr, lane, wv, n0h);
  } else {
    gemm_ks<KT0>(Bbuf, xsl, DIN, 1024, h0cur, 1536, Wc0, 3072, tid, lane, wv, n0h, acc);
    store_partial(acc, p0 + (size_t)cb * 16384, lane, wv);
    publish(f0 + cb, epoch);
  }
}

// Single layer, K-split (schedule edges): grid 128 = 2 halves x 64 cb.
template<int KT>
__global__ __launch_bounds__(256) void lstm_solo_ks(
    const unsigned short* __restrict__ a0, int s0, int ksplit,
    const unsigned short* __restrict__ a1,
    int kofs1,
    const unsigned short* __restrict__ w, int wstr, const float* __restrict__ bias,
    float* __restrict__ c, unsigned short* __restrict__ hout, float* __restrict__ fout,
    float* __restrict__ part, unsigned* __restrict__ flg, unsigned epoch)
{
  __shared__ __align__(16) unsigned short Bbuf[4][128 * 64];   // 64 KB
  const int tid = threadIdx.x, lane = tid & 63, wv = tid >> 6;
  const int half = blockIdx.x >> 6, cb = blockIdx.x & 63, n0h = cb << 5;
  f32x16 acc[4] = {};

  if (half == 0) {
    gemm_ks<KT>(Bbuf, a0, s0, ksplit, a1, 0, w, wstr, tid, lane, wv, n0h, acc);
    await(flg + cb, epoch);
    combine_add(acc, part + (size_t)cb * 16384, lane, wv);
    lstm_epilogue(acc, bias, c, hout, fout, lane, wv, n0h);
  } else {
    gemm_ks<KT>(Bbuf, a0, s0, ksplit, a1, kofs1, w, wstr, tid, lane, wv, n0h, acc);
    store_partial(acc, part + (size_t)cb * 16384, lane, wv);
    publish(flg + cb, epoch);
  }
}

extern "C" void kernel_launch(void* const* d_in, const int* in_sizes, int n_in,
                              void* d_out, int out_size, void* d_ws, size_t ws_size,
                              hipStream_t stream) {
  (void)in_sizes; (void)n_in; (void)out_size; (void)ws_size;
  const float* x    = (const float*)d_in[0];
  const float* h0   = (const float*)d_in[1];
  const float* c0   = (const float*)d_in[2];
  const float* Wih0 = (const float*)d_in[3];
  const float* Whh0 = (const float*)d_in[4];
  const float* b0   = (const float*)d_in[5];
  const float* Wih1 = (const float*)d_in[6];
  const float* Whh1 = (const float*)d_in[7];
  const float* b1   = (const float*)d_in[8];
  float* out = (float*)d_out;

  unsigned short* xbf = (unsigned short*)d_ws;                     // 134 MB
  unsigned short* Wc0 = xbf + (size_t)T_STEPS * B_SZ * DIN;        // 50 MB
  unsigned short* Wc1 = Wc0 + (size_t)NG * 3072;                   // 67 MB
  unsigned short* hb0 = Wc1 + (size_t)NG * 4096;                   // 2*BH
  unsigned short* hb1 = hb0 + 2 * (size_t)BH;                      // 2*BH
  float*          cws = (float*)(hb1 + 2 * (size_t)BH);            // 2*BH fp32
  float*          p1  = cws + 2 * (size_t)BH;                      // 64*16384 fp32 (4MB)
  float*          p0  = p1 + 64 * 16384;                           // 4MB
  unsigned*       flg = (unsigned*)(p0 + 64 * 16384);              // 256 u32
  unsigned* flags1 = flg;          // pair L1
  unsigned* flags0 = flg + 64;     // pair L0
  unsigned* flagsE = flg + 128;    // edges (two banks of 64)

  cvt_x_bf16<<<dim3(4096), dim3(256), 0, stream>>>(
      (const float4*)x, (ushort4*)xbf, T_STEPS * B_SZ * DIN / 4);
  build_wcat<<<dim3(12, NG), dim3(256), 0, stream>>>(Wih0, Whh0, Wc0, DIN, 3072);
  build_wcat<<<dim3(16, NG), dim3(256), 0, stream>>>(Wih1, Whh1, Wc1, H_SZ, 4096);
  init_state<<<dim3(BH / 256), dim3(256), 0, stream>>>(h0, c0, hb0, hb1, cws, flg);

  // Schedule: L0(0); { L1(t) || L0(t+1) } t=0..510; L1(511)->out.
  // h slots: L0(t) reads hb0 slot[t&1], writes slot[(t+1)&1];
  //          L1(t) reads hb0 slot[(t+1)&1] + hb1 slot[t&1], writes hb1 slot[(t+1)&1].
  lstm_solo_ks<24><<<dim3(128), dim3(256), 0, stream>>>(
      xbf, DIN, 1024, hb0 + 0, 1536, Wc0, 3072, b0,
      cws, hb0 + BH, nullptr, p0, flagsE, 1u);

  for (int t = 0; t < T_STEPS - 1; ++t) {
    const unsigned short* h0cur = hb0 + (size_t)((t + 1) & 1) * BH;
    lstm_pair_ks<32, 24><<<dim3(256), dim3(256), 0, stream>>>(
        h0cur, hb1 + (size_t)(t & 1) * BH, Wc1, b1,
        cws + BH, hb1 + (size_t)((t + 1) & 1) * BH,
        xbf + (size_t)(t + 1) * B_SZ * DIN, Wc0, b0,
        cws, hb0 + (size_t)(t & 1) * BH,
        p1, p0, flags1, flags0, (unsigned)(t + 1));
  }
  // L1(511): reads hb0 slot0, hb1 slot1; writes hb1 slot0 + fp32 out.
  lstm_solo_ks<32><<<dim3(128), dim3(256), 0, stream>>>(
      hb0 + 0, H_SZ, 2048, hb1 + BH, 2048, Wc1, 4096, b1,
      cws + BH, hb1 + 0, out, p1, flagsE + 64, 1u);
}